// Round 1
// 1218.856 us; speedup vs baseline: 1.0374x; 1.0374x over previous
//
#include <hip/hip_runtime.h>
#include <stdint.h>
#include <stddef.h>

#define NROWS 32768
#define KCODES 8192
#define DIM 512

/* ---- filter GEMM (8-phase 256^2 pipeline) ---- */
#define BMG 256
#define BNG 256
#define BKG 64
#define KSPLIT 2
#define SEGC (KCODES / KSPLIT)           /* 4096 */
#define NKT (SEGC / BNG)                 /* 16 column tiles per block */
#define NGITER (NKT * (DIM / (2 * BKG))) /* 64 iterations (2 K-tiles each) */
#define NGK (NKT * (DIM / BKG))          /* 128 global K-tiles per block */
#define TAU 1.5e-3f
#define MAXC 64
#define CHAINSPLIT 384 /* OpenBLAS sgemm kc */

typedef __attribute__((ext_vector_type(8))) short short8;
typedef __attribute__((ext_vector_type(4))) float floatx4;
typedef unsigned long long ull;

static __device__ __forceinline__ unsigned short f2bf(float f) {
  unsigned u = __float_as_uint(f);
  unsigned r = (u + 0x7FFFu + ((u >> 16) & 1u)) >> 16;
  return (unsigned short)r;
}
// monotone float->uint key (order-preserving for finite floats)
static __device__ __forceinline__ unsigned fkey(float s) {
  unsigned b = __float_as_uint(s);
  return b ^ (((int)b < 0) ? 0xFFFFFFFFu : 0x80000000u);
}

#define GLDS16(g, l)                                                        \
  __builtin_amdgcn_global_load_lds(                                         \
      (const __attribute__((address_space(1))) unsigned int*)(g),           \
      (__attribute__((address_space(3))) unsigned int*)(l), 16, 0, 0)

// ---------------------------------------------------------------------------
// numpy-exact row norm (unchanged).
// ---------------------------------------------------------------------------
__global__ __launch_bounds__(256) void k_rownorm(const float* __restrict__ x,
                                                 float* __restrict__ nout,
                                                 int nrows,
                                                 int* __restrict__ counts,
                                                 int ninit,
                                                 float* __restrict__ lossacc) {
  const int tid = threadIdx.x;
  const int j = tid & 7;
  const int row = blockIdx.x * 32 + (tid >> 3);
  if (counts != nullptr && j == 0 && row < ninit) counts[row] = 0;
  if (lossacc != nullptr && blockIdx.x == 0 && tid == 0) *lossacc = 0.0f;
  if (row >= nrows) return;
  const float* xr = x + (size_t)row * DIM;
  float blk[4];
#pragma unroll
  for (int b = 0; b < 4; ++b) {
    const float* p = xr + b * 128;
    float r = __fmul_rn(p[j], p[j]);
    for (int i = 8; i < 128; i += 8) {
      const float t = p[i + j];
      r = __fadd_rn(r, __fmul_rn(t, t));
    }
    r = __fadd_rn(r, __shfl_xor(r, 1, 64));
    r = __fadd_rn(r, __shfl_xor(r, 2, 64));
    r = __fadd_rn(r, __shfl_xor(r, 4, 64));
    blk[b] = r;
  }
  const float tot =
      __fadd_rn(__fadd_rn(blk[0], blk[1]), __fadd_rn(blk[2], blk[3]));
  if (j == 0) nout[row] = fmaxf(__fsqrt_rn(tot), 1e-12f);
}

// ---------------------------------------------------------------------------
// Normalized rows (unchanged).
// ---------------------------------------------------------------------------
__global__ __launch_bounds__(256) void k_normstore(const float* __restrict__ x,
                                                   const float* __restrict__ nin,
                                                   unsigned short* __restrict__ xb,
                                                   float* __restrict__ xf) {
  const int wv = threadIdx.x >> 6;
  const int lane = threadIdx.x & 63;
  const int row = blockIdx.x * 4 + wv;
  const float n = nin[row];
  const float4* xr = (const float4*)(x + (size_t)row * DIM);
#pragma unroll
  for (int h = 0; h < 2; ++h) {
    const float4 v = xr[lane + 64 * h];
    const float q0 = __fdiv_rn(v.x, n);
    const float q1 = __fdiv_rn(v.y, n);
    const float q2 = __fdiv_rn(v.z, n);
    const float q3 = __fdiv_rn(v.w, n);
    if (xf != nullptr)
      ((float4*)(xf + (size_t)row * DIM))[lane + 64 * h] =
          make_float4(q0, q1, q2, q3);
    *(ushort4*)(xb + (size_t)row * DIM + 256 * h + 4 * lane) =
        make_ushort4(f2bf(q0), f2bf(q1), f2bf(q2), f2bf(q3));
  }
}

// ---------------------------------------------------------------------------
// bf16 MFMA filter GEMM, 8-phase 256x256 double-buffered pipeline (T2+T3+T4+T5).
// 8 waves (2M x 4N), per-wave 128x64 output, BK=64, 8 LDS slots x 16KB.
// Iteration g computes K-tiles {2g,2g+1}; prefetch of K-tile (2g+1) issues at
// phase 0 (slots 4-7), K-tile (2g+2) at phase 4 (slots 0-3); vmcnt(0) only at
// phases 3 and 7 -> loads span ~4 MFMA phases. Barriers make slot reuse safe:
// a slot's last ds_read is always before the barrier preceding its re-stage.
// LDS granule-XOR swizzle (T2-equivalent) via pre-swizzled global source,
// identical to the previous (bank-conflict-free) kernel. Per 256-col tile:
// wave-local 16-lane row max -> cross-wave LDS combine -> running-max - TAU
// threshold -> atomic candidate collect (same semantics as before; the tile
// argmax always passes its own tile threshold, so the true max is collected).
// Grid: (128, KSPLIT=2) = 256 blocks = 1/CU; bijective XCD swizzle maps each
// XCD to one 4MB cnb segment (fits per-XCD L2).
// ---------------------------------------------------------------------------
__global__ __launch_bounds__(512, 2) void k_gemm_collect(
    const unsigned short* __restrict__ znb, const unsigned short* __restrict__ cnb,
    int* __restrict__ counts, int* __restrict__ cands) {
  __shared__ __align__(16) short lds[8 * 8192]; /* 8 slots x 16KB = 128KB */
  __shared__ __align__(16) float redm[256][4];  /* per-wave row maxes */
  __shared__ float runm[256];                   /* running row max (this seg) */

  const int tid = threadIdx.x;
  const int lane = tid & 63;
  const int w = tid >> 6; /* wave 0..7 */
  const int wr = w >> 2;  /* M half: rows wr*128.. */
  const int wc = w & 3;   /* N quarter: cols wc*64.. */
  const int l15 = lane & 15;
  const int l4 = lane >> 4;

  /* XCD-aware bijective swizzle: 256 blocks -> 32 contiguous per XCD */
  const int bid = blockIdx.y * (NROWS / BMG) + blockIdx.x;
  const int logical = (bid & 7) * 32 + (bid >> 3);
  const int row0 = (logical & (NROWS / BMG - 1)) * BMG;
  const int seg0 = (logical >> 7) * SEGC;

  auto stage_ktile = [&](int gk) {
    if (gk >= NGK) gk -= 2; /* tail: idempotent re-stage of same slots */
    const int d0 = (gk & 7) * BKG;
    const int sb = (gk & 1) * 4;
    const int cb0 = seg0 + (gk >> 3) * BNG;
#pragma unroll
    for (int kind = 0; kind < 4; ++kind) {
      const unsigned short* src = (kind < 2) ? znb : cnb;
      const int grow0 = (kind < 2) ? (row0 + kind * 128) : (cb0 + (kind - 2) * 128);
#pragma unroll
      for (int l = 0; l < 2; ++l) {
        const int g = (l * 8 + w) * 64 + lane; /* granule id 0..1023 */
        const int r = g >> 3;                  /* half-tile row */
        const int cg = (g & 7) ^ (r & 7);      /* pre-swizzled source granule */
        GLDS16(src + (size_t)(grow0 + r) * DIM + d0 + cg * 8,
               lds + (sb + kind) * 8192 + (l * 8 + w) * 512);
      }
    }
  };

  for (int x = tid; x < 256; x += 512) runm[x] = -2.0f;

  floatx4 acc[8][4];
#pragma unroll
  for (int i = 0; i < 8; ++i)
#pragma unroll
    for (int n = 0; n < 4; ++n) {
      floatx4 zz = {0.f, 0.f, 0.f, 0.f};
      acc[i][n] = zz;
    }

  /* prologue: K-tile 0 into slots 0-3 */
  stage_ktile(0);
  asm volatile("s_waitcnt vmcnt(0)" ::: "memory");
  __builtin_amdgcn_s_barrier();

  short8 bf[4][2]; /* B frags held across the 4 phases of a K-tile */
  for (int giter = 0; giter < NGITER; ++giter) {
#pragma unroll
    for (int p = 0; p < 8; ++p) {
      const int half = p >> 2; /* which K-tile of the pair */
      const int q = p & 3;     /* M-quarter */
      const int sb = half * 4;
      if (q == 0) {
        /* issue next K-tile's 4 half-tiles (8 glds): p0 -> slots 4-7,
           p4 -> slots 0-3; both strictly after the last reads of those slots */
        stage_ktile(2 * giter + 1 + half);
#pragma unroll
        for (int n = 0; n < 4; ++n)
#pragma unroll
          for (int kk2 = 0; kk2 < 2; ++kk2) {
            const int rb = (wc & 1) * 64 + n * 16 + l15;
            bf[n][kk2] = *(const short8*)&lds[(sb + 2 + (wc >> 1)) * 8192 +
                                              rb * 64 +
                                              (((l4 + kk2 * 4) ^ (rb & 7)) << 3)];
          }
      }
      short8 af[2][2];
#pragma unroll
      for (int ii = 0; ii < 2; ++ii)
#pragma unroll
        for (int kk2 = 0; kk2 < 2; ++kk2) {
          const int ra = (2 * q + ii) * 16 + l15;
          af[ii][kk2] = *(const short8*)&lds[(sb + wr) * 8192 + ra * 64 +
                                             (((l4 + kk2 * 4) ^ (ra & 7)) << 3)];
        }
      __builtin_amdgcn_s_barrier();
      asm volatile("s_waitcnt lgkmcnt(0)" ::: "memory");
      __builtin_amdgcn_s_setprio(1);
#pragma unroll
      for (int ii = 0; ii < 2; ++ii)
#pragma unroll
        for (int n = 0; n < 4; ++n)
#pragma unroll
          for (int kk2 = 0; kk2 < 2; ++kk2)
            acc[2 * q + ii][n] = __builtin_amdgcn_mfma_f32_16x16x32_bf16(
                af[ii][kk2], bf[n][kk2], acc[2 * q + ii][n], 0, 0, 0);
      __builtin_amdgcn_s_setprio(0);
      if (q == 3) asm volatile("s_waitcnt vmcnt(0)" ::: "memory");
      __builtin_amdgcn_s_barrier();
    }

    /* ---- per-column-tile collect epilogue (every 4 iterations) ---- */
    if ((giter & 3) == 3) {
      const int col0 = seg0 + (giter >> 2) * BNG;
      /* step A: wave-local per-row max over this wave's 64 cols */
#pragma unroll
      for (int i = 0; i < 8; ++i)
#pragma unroll
        for (int r = 0; r < 4; ++r) {
          float v = fmaxf(fmaxf(acc[i][0][r], acc[i][1][r]),
                          fmaxf(acc[i][2][r], acc[i][3][r]));
#pragma unroll
          for (int off = 1; off < 16; off <<= 1)
            v = fmaxf(v, __shfl_xor(v, off, 64));
          if (l15 == 0) redm[wr * 128 + i * 16 + l4 * 4 + r][wc] = v;
        }
      __syncthreads();
      /* step B: cross-wave max + threshold + collect (reads old runm) */
#pragma unroll
      for (int i = 0; i < 8; ++i)
#pragma unroll
        for (int r = 0; r < 4; ++r) {
          const int rowt = wr * 128 + i * 16 + l4 * 4 + r;
          const float4 m4 = *(const float4*)redm[rowt];
          const float nm = fmaxf(
              runm[rowt], fmaxf(fmaxf(m4.x, m4.y), fmaxf(m4.z, m4.w)));
          const float th = nm - TAU;
          const int rowg = row0 + rowt;
#pragma unroll
          for (int n = 0; n < 4; ++n) {
            if (acc[i][n][r] >= th) {
              const int slot = atomicAdd(&counts[rowg], 1);
              if (slot < MAXC)
                cands[rowg * MAXC + slot] = col0 + wc * 64 + n * 16 + l15;
            }
          }
#pragma unroll
          for (int n = 0; n < 4; ++n) acc[i][n][r] = 0.f;
        }
      __syncthreads();
      /* step C: designated lanes update running max (recompute, no regs held) */
      if (wc == 0 && l15 == 0) {
#pragma unroll
        for (int i = 0; i < 8; ++i)
#pragma unroll
          for (int r = 0; r < 4; ++r) {
            const int rowt = wr * 128 + i * 16 + l4 * 4 + r;
            const float4 m4 = *(const float4*)redm[rowt];
            runm[rowt] = fmaxf(
                runm[rowt], fmaxf(fmaxf(m4.x, m4.y), fmaxf(m4.z, m4.w)));
          }
      }
    }
  }
}

// ---------------------------------------------------------------------------
// fp32-EMULATED rescore (unchanged).
// ---------------------------------------------------------------------------
__global__ __launch_bounds__(256) void k_rescore(
    const float* __restrict__ z, const float* __restrict__ normz,
    const float* __restrict__ cnf, const int* __restrict__ counts,
    const int* __restrict__ cands, int* __restrict__ bestk) {
  __shared__ float zn[4][DIM];
  const int wv = threadIdx.x >> 6;
  const int lane = threadIdx.x & 63;
  const int row = blockIdx.x * 4 + wv;
  const float n = normz[row];
  const float* zr = z + (size_t)row * DIM;
#pragma unroll
  for (int j = 0; j < 8; ++j) {
    const int d = lane * 8 + j;
    zn[wv][d] = __fdiv_rn(zr[d], n);
  }
  __syncthreads();
  const int cnt = counts[row];
  const bool fullscan = (cnt <= 0) || (cnt > MAXC);
  ull best = 0ull;
  if (!fullscan) {
    const int idx = (lane < cnt) ? lane : (cnt - 1);
    const int k = cands[row * MAXC + idx] & (KCODES - 1);
    const float* cr = cnf + (size_t)k * DIM;
    float a1 = 0.f, a2 = 0.f;
    for (int d = 0; d < CHAINSPLIT; d += 4) {
      const float4 c = *(const float4*)(cr + d);
      a1 = fmaf(zn[wv][d], c.x, a1);
      a1 = fmaf(zn[wv][d + 1], c.y, a1);
      a1 = fmaf(zn[wv][d + 2], c.z, a1);
      a1 = fmaf(zn[wv][d + 3], c.w, a1);
    }
    for (int d = CHAINSPLIT; d < DIM; d += 4) {
      const float4 c = *(const float4*)(cr + d);
      a2 = fmaf(zn[wv][d], c.x, a2);
      a2 = fmaf(zn[wv][d + 1], c.y, a2);
      a2 = fmaf(zn[wv][d + 2], c.z, a2);
      a2 = fmaf(zn[wv][d + 3], c.w, a2);
    }
    const float s = __fadd_rn(a1, a2);
    if (lane < cnt) best = ((ull)fkey(s) << 32) | (ull)(8191 - k);
  } else {
    for (int base = 0; base < KCODES; base += 64) {
      const int k = base + lane;
      const float* cr = cnf + (size_t)k * DIM;
      float a1 = 0.f, a2 = 0.f;
      for (int d = 0; d < CHAINSPLIT; d += 4) {
        const float4 c = *(const float4*)(cr + d);
        a1 = fmaf(zn[wv][d], c.x, a1);
        a1 = fmaf(zn[wv][d + 1], c.y, a1);
        a1 = fmaf(zn[wv][d + 2], c.z, a1);
        a1 = fmaf(zn[wv][d + 3], c.w, a1);
      }
      for (int d = CHAINSPLIT; d < DIM; d += 4) {
        const float4 c = *(const float4*)(cr + d);
        a2 = fmaf(zn[wv][d], c.x, a2);
        a2 = fmaf(zn[wv][d + 1], c.y, a2);
        a2 = fmaf(zn[wv][d + 2], c.z, a2);
        a2 = fmaf(zn[wv][d + 3], c.w, a2);
      }
      const float s = __fadd_rn(a1, a2);
      const ull q = ((ull)fkey(s) << 32) | (ull)(8191 - k);
      best = (q > best) ? q : best;
    }
  }
#pragma unroll
  for (int off = 1; off < 64; off <<= 1) {
    const ull o = __shfl_xor(best, off, 64);
    best = (o > best) ? o : best;
  }
  if (lane == 0) bestk[row] = 8191 - (int)(best & 0xFFFFFFFFull);
}

// ---------------------------------------------------------------------------
// Output (unchanged).
// ---------------------------------------------------------------------------
__global__ __launch_bounds__(256) void k_output(
    const float* __restrict__ z, const float* __restrict__ normz,
    const float* __restrict__ cnf, const int* __restrict__ bestk,
    float* __restrict__ out, float* __restrict__ lossacc) {
  const int wv = threadIdx.x >> 6;
  const int lane = threadIdx.x & 63;
  const int row = blockIdx.x * 4 + wv;
  const int k = bestk[row];
  const float n = normz[row];
  const float4* cr = (const float4*)(cnf + (size_t)k * DIM);
  const float4* zr = (const float4*)(z + (size_t)row * DIM);
  float ss = 0.0f;
  float4* orow = (float4*)(out + (size_t)row * DIM);
#pragma unroll
  for (int h = 0; h < 2; ++h) {
    const float4 q = cr[lane + 64 * h];
    const float4 zv = zr[lane + 64 * h];
    orow[lane + 64 * h] = q;
    const float d0 = q.x - __fdiv_rn(zv.x, n);
    const float d1 = q.y - __fdiv_rn(zv.y, n);
    const float d2 = q.z - __fdiv_rn(zv.z, n);
    const float d3 = q.w - __fdiv_rn(zv.w, n);
    ss += d0 * d0 + d1 * d1 + d2 * d2 + d3 * d3;
  }
#pragma unroll
  for (int off = 1; off < 64; off <<= 1) ss += __shfl_xor(ss, off, 64);
  if (lane == 0) {
    atomicAdd(lossacc, ss);
    out[(size_t)NROWS * DIM + row] = (float)k;
  }
}

__global__ void k_loss_final(const float* __restrict__ lossacc,
                             float* __restrict__ out) {
  if (threadIdx.x == 0 && blockIdx.x == 0)
    out[(size_t)NROWS * DIM + NROWS] =
        1.5f * (*lossacc) / (float)((size_t)NROWS * DIM);
}

// ---------------------------------------------------------------------------
extern "C" void kernel_launch(void* const* d_in, const int* in_sizes, int n_in,
                              void* d_out, int out_size, void* d_ws, size_t ws_size,
                              hipStream_t stream) {
  const float* z = (const float*)d_in[0];
  const float* cb = (const float*)d_in[1];
  char* ws = (char*)d_ws;
  // workspace layout, ~64.5 MB total
  float* normz = (float*)(ws);                             // 131072
  float* normc = (float*)(ws + 131072);                    // 32768
  int* counts = (int*)(ws + 163840);                       // 131072
  int* bestk = (int*)(ws + 294912);                        // 131072
  float* lossacc = (float*)(ws + 425984);                  // 4 (padded)
  int* cands = (int*)(ws + 458752);                        // 8388608
  unsigned short* znb = (unsigned short*)(ws + 8847360);   // 33554432
  unsigned short* cnb = (unsigned short*)(ws + 42401792);  // 8388608
  float* cnf = (float*)(ws + 50790400);                    // 16777216
  float* out = (float*)d_out;

  k_rownorm<<<dim3(NROWS / 32), dim3(256), 0, stream>>>(z, normz, NROWS, counts,
                                                        NROWS, lossacc);
  k_rownorm<<<dim3(KCODES / 32), dim3(256), 0, stream>>>(cb, normc, KCODES,
                                                         (int*)nullptr, 0,
                                                         (float*)nullptr);
  k_normstore<<<dim3(NROWS / 4), dim3(256), 0, stream>>>(z, normz, znb,
                                                         (float*)nullptr);
  k_normstore<<<dim3(KCODES / 4), dim3(256), 0, stream>>>(cb, normc, cnb, cnf);
  k_gemm_collect<<<dim3(NROWS / BMG, KSPLIT), dim3(512), 0, stream>>>(znb, cnb,
                                                                      counts, cands);
  k_rescore<<<dim3(NROWS / 4), dim3(256), 0, stream>>>(z, normz, cnf, counts,
                                                       cands, bestk);
  k_output<<<dim3(NROWS / 4), dim3(256), 0, stream>>>(z, normz, cnf, bestk, out,
                                                      lossacc);
  k_loss_final<<<dim3(1), dim3(64), 0, stream>>>(lossacc, out);
}